// Round 1
// baseline (4981.189 us; speedup 1.0000x reference)
//
#include <hip/hip_runtime.h>

#define T_SAVE 128
#define D_DIM 32
#define BT 16
#define NTHREADS 512

typedef __attribute__((ext_vector_type(8))) short short8;
typedef __attribute__((ext_vector_type(4))) float f32x4;

__device__ __forceinline__ short f2bf(float x) {
    union { float f; unsigned u; } v; v.f = x;
    return (short)((v.u + 0x7fffu + ((v.u >> 16) & 1u)) >> 16);  // RTN-even
}

__device__ __forceinline__ float softplus_f(float x) {
    return fmaxf(x, 0.0f) + __logf(1.0f + __expf(-fabsf(x)));
}

// Tsit5 stage coefficient table: TA[st-1][j] for stage st's dependence on k_j
static __device__ const float TA[5][5] = {
    {0.161f, 0.f, 0.f, 0.f, 0.f},
    {-0.008480655492356989f, 0.335480655492357f, 0.f, 0.f, 0.f},
    {2.8971530571054935f, -6.359448489975075f, 4.3622954328695815f, 0.f, 0.f},
    {5.325864828439257f, -11.748883564062828f, 7.4955393428898365f, -0.09249506636175525f, 0.f},
    {5.86145544294642f, -12.92096931784711f, 8.159367898576159f, -0.071584973281401f, -0.028269050394068383f}
};

__global__ __launch_bounds__(NTHREADS, 2)
void node_mfma(const float* __restrict__ ts, const float* __restrict__ y0,
               const float* __restrict__ Win, const float* __restrict__ bin,
               const float* __restrict__ Wh, const float* __restrict__ bh,
               const float* __restrict__ Wout, const float* __restrict__ bout,
               float* __restrict__ out)
{
    // fp32 state + stage derivatives, pad 36 (2-way LDS aliasing only = free)
    __shared__ __align__(16) float sy[BT][36];
    __shared__ __align__(16) float sk[6][BT][36];
    // bf16 hidden activation ping-pong tiles, row stride 136 (16B-aligned rows, 2-way banks)
    __shared__ __align__(16) short sha[BT * 136];
    __shared__ __align__(16) short shb[BT * 136];
    __shared__ float sts[T_SAVE];

    const int tid  = threadIdx.x;
    const int wave = tid >> 6;
    const int lane = tid & 63;
    const int n    = lane & 15;      // MFMA A-row (sample) and B-col (output) index
    const int q    = lane >> 4;      // quad: A/B k = 8q+j ; C/D rows = 4q+reg
    const int r    = 16 * wave + n;  // this wave's output-feature row in [0,128)
    const int s0   = blockIdx.x * BT;

    // ---- one-time: weight fragments into registers (B-operand layout: B[n][k], k-contig) ----
    short8 winf;
    short8 whf[2][4];
    short8 woutf[4] = {};
    #pragma unroll
    for (int j = 0; j < 8; ++j) winf[j] = f2bf(Win[r * 32 + 8 * q + j]);
    #pragma unroll
    for (int L = 0; L < 2; ++L)
        #pragma unroll
        for (int c = 0; c < 4; ++c)
            #pragma unroll
            for (int j = 0; j < 8; ++j)
                whf[L][c][j] = f2bf(Wh[L * 16384 + r * 128 + 32 * c + 8 * q + j]);
    float boutr = 0.f;
    if (wave < 2) {  // only waves 0,1 own output-layer rows (D=32)
        #pragma unroll
        for (int c = 0; c < 4; ++c)
            #pragma unroll
            for (int j = 0; j < 8; ++j)
                woutf[c][j] = f2bf(Wout[r * 128 + 32 * c + 8 * q + j]);
        boutr = bout[r];
    }
    const float binr = bin[r];
    const float bhr0 = bh[r];
    const float bhr1 = bh[128 + r];

    // ---- init: stage y0 into LDS, emit t=0 output, cache ts ----
    {
        const int s = tid >> 5, d = tid & 31;
        float v = y0[(s0 + s) * D_DIM + d];
        sy[s][d] = v;
        out[(size_t)(s0 + s) * (T_SAVE * D_DIM) + d] = v;
    }
    if (tid < T_SAVE) sts[tid] = ts[tid];
    __syncthreads();

    auto hidden = [&](const short* src, short* dst, const short8* wf, float bias) {
        f32x4 acc = {0.f, 0.f, 0.f, 0.f};
        #pragma unroll
        for (int c = 0; c < 4; ++c) {
            short8 a = *(const short8*)(src + n * 136 + 32 * c + 8 * q);
            acc = __builtin_amdgcn_mfma_f32_16x16x32_bf16(a, wf[c], acc, 0, 0, 0);
        }
        #pragma unroll
        for (int rr = 0; rr < 4; ++rr)  // C layout: row = 4q+rr (sample), col = r
            dst[(4 * q + rr) * 136 + r] = f2bf(softplus_f(acc[rr] + bias));
        __syncthreads();
    };

    for (int ti = 0; ti < T_SAVE - 1; ++ti) {
        const float hsub = (sts[ti + 1] - sts[ti]) * 0.25f;
        #pragma unroll 1
        for (int sub = 0; sub < 4; ++sub) {
            #pragma unroll
            for (int st = 0; st < 6; ++st) {
                // ---- self-build A fragment: ystage[m=n][k=8q+j], fp32 -> bf16 ----
                float v[8];
                {
                    const float* yp = &sy[n][8 * q];
                    f32x4 a0 = *(const f32x4*)yp;
                    f32x4 a1 = *(const f32x4*)(yp + 4);
                    #pragma unroll
                    for (int j = 0; j < 4; ++j) { v[j] = a0[j]; v[j + 4] = a1[j]; }
                }
                #pragma unroll
                for (int jj = 0; jj < 5; ++jj) {
                    if (jj < st) {
                        const float c = hsub * TA[st - 1][jj];
                        const float* kp = &sk[jj][n][8 * q];
                        f32x4 k0 = *(const f32x4*)kp;
                        f32x4 k1 = *(const f32x4*)(kp + 4);
                        #pragma unroll
                        for (int j = 0; j < 4; ++j) { v[j] += c * k0[j]; v[j + 4] += c * k1[j]; }
                    }
                }
                short8 afrag;
                #pragma unroll
                for (int j = 0; j < 8; ++j) afrag[j] = f2bf(v[j]);

                // ---- input layer: [16,32] x Win^T -> sha ----
                f32x4 acc = {0.f, 0.f, 0.f, 0.f};
                acc = __builtin_amdgcn_mfma_f32_16x16x32_bf16(afrag, winf, acc, 0, 0, 0);
                #pragma unroll
                for (int rr = 0; rr < 4; ++rr)
                    sha[(4 * q + rr) * 136 + r] = f2bf(softplus_f(acc[rr] + binr));
                __syncthreads();

                hidden(sha, shb, whf[0], bhr0);  // h1: sha -> shb
                hidden(shb, sha, whf[1], bhr1);  // h2: shb -> sha

                // ---- output layer: k_st = Wout·h3 + bout (waves 0,1), fp32 into sk ----
                if (wave < 2) {
                    f32x4 oc = {0.f, 0.f, 0.f, 0.f};
                    #pragma unroll
                    for (int c = 0; c < 4; ++c) {
                        short8 a = *(const short8*)(sha + n * 136 + 32 * c + 8 * q);
                        oc = __builtin_amdgcn_mfma_f32_16x16x32_bf16(a, woutf[c], oc, 0, 0, 0);
                    }
                    #pragma unroll
                    for (int rr = 0; rr < 4; ++rr)
                        sk[st][4 * q + rr][r] = oc[rr] + boutr;
                }
                __syncthreads();
            }
            // ---- Tsit5 combine: y += h * sum(B_i k_i) ----
            {
                const int s = tid >> 5, d = tid & 31;
                float yv = sy[s][d];
                yv += hsub * (0.09646076681806523f  * sk[0][s][d]
                            + 0.01f                 * sk[1][s][d]
                            + 0.4798896504144996f   * sk[2][s][d]
                            + 1.379008574103742f    * sk[3][s][d]
                            + (-3.290069515436081f) * sk[4][s][d]
                            + 2.324710524099774f    * sk[5][s][d]);
                sy[s][d] = yv;
            }
            __syncthreads();
        }
        // ---- save point t = ti+1 ----
        {
            const int s = tid >> 5, d = tid & 31;
            out[(size_t)(s0 + s) * (T_SAVE * D_DIM) + (ti + 1) * D_DIM + d] = sy[s][d];
        }
    }
}

extern "C" void kernel_launch(void* const* d_in, const int* in_sizes, int n_in,
                              void* d_out, int out_size, void* d_ws, size_t ws_size,
                              hipStream_t stream) {
    const float* ts   = (const float*)d_in[0];
    const float* y0   = (const float*)d_in[1];
    const float* Win  = (const float*)d_in[2];
    const float* bin  = (const float*)d_in[3];
    const float* Wh   = (const float*)d_in[4];
    const float* bh   = (const float*)d_in[5];
    const float* Wout = (const float*)d_in[6];
    const float* bout = (const float*)d_in[7];
    float* out = (float*)d_out;

    const int Btot = in_sizes[1] / D_DIM;  // 4096
    dim3 grid(Btot / BT), block(NTHREADS);
    node_mfma<<<grid, block, 0, stream>>>(ts, y0, Win, bin, Wh, bh, Wout, bout, out);
}